// Round 5
// baseline (373.489 us; speedup 1.0000x reference)
//
#include <hip/hip_runtime.h>
#include <cstddef>

#define B 2048
#define T 128
#define S 16
#define NL 128
#define IN 32
#define OUT 8
#define DT 0.01f

// Rinn branch: 7 fixed-point iterations per t, THREE timesteps software-
// pipelined, 3 rounds per t (390 rounds total vs 516 at 2-deep): per window w
//   j0: i1(w) || i4(w-1) || i7(w-2)          (+ y(w+2) global-load issue)
//   j1: i2(w) || i5(w-1) || epilogue(w-2)    (ep -> u out, x_{w-1})
//   j2: i3(w) || i6-exact(w-1)               (+ y(w+2) LDS write)
// i1-i5 use cstx extrapolated 2 steps (3*cstx(x_{w-2})-2*cstx(x_{w-3}), same
// stencil as the 2-deep version); i6 recomputes the exact cst from x_{w-1}
// (written by ep one barrier earlier), i7 keeps it.  Error: 2 exact iters
// contract the approx-cst fixed-point shift by rho^2 ~ 0.42 -> ~0.012, on par
// with the measured 0.031 absmax.  Round latency is dominated by a ~700cy
// fixed dep-chain+barrier cost (measured 1190cy/round at 2 work-units), so
// packing 2.5 units/round on average cuts total time ~proportionally.

#define NBLK_R (B / 16)          // 128 rinn blocks, 16 batch rows each
#define NBLK_V ((B * T) / 512)   // 512 value blocks, 512 samples each
#define NTHR 512

typedef unsigned int uint;
typedef _Float16 f16;
typedef f16 f16x8 __attribute__((ext_vector_type(8)));
typedef __fp16 fp16x2_n __attribute__((ext_vector_type(2)));  // native cvt_pkrtz type
typedef float f32x4 __attribute__((ext_vector_type(4)));

union ABu { f16x8 v; f16 h[8]; };

#define MFMA16(A, Bv, C) __builtin_amdgcn_mfma_f32_16x16x32_f16((A), (Bv), (C), 0, 0, 0)

__device__ __forceinline__ uint pkrtz_u(float a, float b) {
    fp16x2_n p = __builtin_amdgcn_cvt_pkrtz(a, b);
    return __builtin_bit_cast(uint, p);
}

// value branch tanh (has slack, keep safe clamp)
__device__ __forceinline__ float fast_tanh(float x) {
    float e = __expf(fminf(x, 10.f) * 2.f);
    return fmaf(-2.f, __builtin_amdgcn_rcpf(e + 1.f), 1.f);
}

// paired tanh -> packed half2, one shared v_rcp
__device__ __forceinline__ uint tanh2_pk(float a, float b) {
    float ea = __expf(a * 2.f);
    float eb = __expf(b * 2.f);
    float da = ea + 1.f, db = eb + 1.f;
    float r  = __builtin_amdgcn_rcpf(da * db);
    float ta = fmaf(-2.f, db * r, 1.f);
    float tb = fmaf(-2.f, da * r, 1.f);
    return pkrtz_u(ta, tb);
}

// LDS chunk layout for a 16(m) x K(k) fp16 matrix: chunk (cc=k>>3, m) holds 8
// consecutive k of row m at byte ((cc*16+m)*16 + (k&7)*2).  B-fragment read for
// MFMA k-step s (quad q, lane m=l15): one ds_read_b128 at ((s*4+q)*16+m)*16.

struct __align__(16) RinnS {
    char wbufs[3][2][4096];  // per-chain-slot (t%3) w ping-pong buffers
    char xbuf[2][1024];      // x_t (f16, K=32 with k>=16 zero pad), per t parity
    char ybuf[4][1024];      // y_t (f16, K=32), ring of 4
    float xs[16][16];        // fp32 master copy of state
};
struct __align__(16) ValueS {
    char scr[8][2048];       // per-wave h^T bounce scratch (64k x 16m fp16)
};
union SmU { RinnS r; ValueS v; };

#define LOAD_W(rb, A0, A1, A2, A3) do { const char* _p = (rb);                 \
    A0 = *(const f16x8*)(_p + rd_off);        A1 = *(const f16x8*)(_p + rd_off + 1024); \
    A2 = *(const f16x8*)(_p + rd_off + 2048); A3 = *(const f16x8*)(_p + rd_off + 3072); } while (0)

#define ITER_BODY(CST, A0, A1, A2, A3, WDST) do {                              \
    f32x4 _p0 = (CST), _p1 = {0.f, 0.f, 0.f, 0.f};                             \
    _p0 = MFMA16(D[0].v, A0, _p0); _p1 = MFMA16(D[1].v, A1, _p1);              \
    _p0 = MFMA16(D[2].v, A2, _p0); _p1 = MFMA16(D[3].v, A3, _p1);              \
    f32x4 _z = _p0 + _p1;                                                      \
    uint2 _w; _w.x = tanh2_pk(_z.x, _z.y); _w.y = tanh2_pk(_z.z, _z.w);        \
    *(uint2*)((WDST) + wa) = _w; } while (0)

__global__ void __launch_bounds__(NTHR, 1)
fused_kernel(const float* __restrict__ obs, const float* __restrict__ x0,
             const float* __restrict__ A_T, const float* __restrict__ Bw_T,
             const float* __restrict__ By_T, const float* __restrict__ Cv_T,
             const float* __restrict__ Dvw_T, const float* __restrict__ Dvy_T,
             const float* __restrict__ Cu_T, const float* __restrict__ Duw_T,
             const float* __restrict__ Duy_T, const float* __restrict__ log_stds,
             const float* __restrict__ W0, const float* __restrict__ b0,
             const float* __restrict__ W1, const float* __restrict__ b1,
             const float* __restrict__ W2, const float* __restrict__ b2,
             float* __restrict__ out) {
    __shared__ SmU sm;
    const int tid = threadIdx.x;
    const int wave = tid >> 6, lane = tid & 63;
    const int q = lane >> 4, l15 = lane & 15;
    const int rd_off = (q * 16 + l15) * 16;  // + s*1024

    if (blockIdx.x < NBLK_R) {
        // ======================= recurrent branch =======================
        RinnS& R = sm.r;
        const int b0r = blockIdx.x * 16;
        const int ct = wave * 16;   // this wave's single 16-col tile of NL

        // ---- iteration-invariant A-operand fragments (fp16) ----
        // Z^T = Dvw^T (A) * w^T (B);  A[c_local][k]: c=ct+l15, k=32s+8q+j
        ABu D[4];
#pragma unroll
        for (int s2 = 0; s2 < 4; ++s2)
#pragma unroll
            for (int j = 0; j < 8; ++j) {
                int k = 32 * s2 + 8 * q + j;
                D[s2].h[j] = (f16)Dvw_T[k * NL + ct + l15];
            }
        // cstx^T = Cv^T (A, K=32 padded) * x^T ; csty^T = Dvy^T (A, K=32) * y^T
        ABu Cx, Cy;
#pragma unroll
        for (int j = 0; j < 8; ++j) {
            int k = 8 * q + j;
            Cx.h[j] = (f16)((k < 16) ? Cv_T[k * NL + ct + l15] : 0.f);
            Cy.h[j] = (f16)Dvy_T[k * NL + ct + l15];
        }
        // epilogue: [u|xn]^T = W^T (A) * [x(32)|y(32)|w(128)]^T (B), K=192
        ABu EPf[6];
        if (wave < 2) {
            int oc = wave * 16 + l15;  // 0..7=u, 8..23=xnext, >=24 pad
#pragma unroll
            for (int s2 = 0; s2 < 6; ++s2)
#pragma unroll
                for (int j = 0; j < 8; ++j) {
                    int k = 32 * s2 + 8 * q + j;
                    float v = 0.f;
                    if (oc < 24) {
                        if (k < 16)       v = (oc < 8) ? Cu_T[k * OUT + oc] : A_T[k * S + (oc - 8)];
                        else if (k >= 32 && k < 64) { int ky = k - 32;
                                          v = (oc < 8) ? Duy_T[ky * OUT + oc] : By_T[ky * S + (oc - 8)]; }
                        else if (k >= 64) { int kw = k - 64;
                                          v = (oc < 8) ? Duw_T[kw * OUT + oc] : Bw_T[kw * S + (oc - 8)]; }
                    }
                    EPf[s2].h[j] = (f16)v;
                }
        }

        // ---- init staging: xs, xbuf[0]=xbuf[1]=x0 (+zero pads), ybuf[0/1]=y0/y1
        if (tid < 256) { int m = tid >> 4, c = tid & 15; R.xs[m][c] = x0[(b0r + m) * S + c]; }
        if (tid < 128) {
            int m = tid >> 3, pr = tid & 7, k = 2 * pr;
            uint u = pkrtz_u(x0[(b0r + m) * S + k], x0[(b0r + m) * S + k + 1]);
            uint off = ((k >> 3) * 16 + m) * 16 + (k & 7) * 2;
            *(uint*)(R.xbuf[0] + off) = u;
            *(uint*)(R.xbuf[1] + off) = u;
        } else if (tid < 384) {   // zero pads: bytes 512..1023 of both xbufs
            int i = tid - 128, buf = i >> 7, d = i & 127;
            *(uint*)(R.xbuf[buf] + 512 + d * 4) = 0u;
        }
        {   // ybuf[0] <- y(0), ybuf[1] <- y(1): 512 pair-slots, one per thread
            int buf = tid >> 8, ii = tid & 255, m = ii >> 4, pr = ii & 15, k = 2 * pr;
            const float* yp = obs + ((size_t)(b0r + m) * T + buf) * IN + k;
            *(uint*)(R.ybuf[buf] + ((k >> 3) * 16 + m) * 16 + (k & 7) * 2) =
                pkrtz_u(yp[0], yp[1]);
        }

        const int wa = (((ct >> 3) + (q >> 1)) * 16 + l15) * 16 + (q & 1) * 8;
        __syncthreads();

        const f32x4 zero4 = {0.f, 0.f, 0.f, 0.f};
        f32x4 cst_y = zero4, cst_m = zero4, cst_o = zero4;
        f32x4 csty_y = zero4, csty_m = zero4;
        f32x4 hx1 = zero4, hx2 = zero4;

        for (int w = 0; w < T + 2; ++w) {
            const bool hy = (w < T);               // young chain t=w: i1..i3
            const bool hm = (w >= 1 && w <= T);    // middle t=w-1: i4..i6
            const bool ho = (w >= 2 && w <= T + 1);// old t=w-2: i7 + ep
            const int slY = w % 3, slM = (w + 2) % 3, slO = (w + 1) % 3;
            float ys0 = 0.f, ys1 = 0.f;
            int ywoff = 0;

            // ---------- j0: i1(w) || i4(w-1) || i7(w-2); y-load issue
            {
                if (hy && tid < 256) {   // y(w+2) load -> regs (LDS write at j2)
                    int m2 = tid >> 4, pr = tid & 15, k = 2 * pr;
                    int tt = (w + 2 < T) ? (w + 2) : (T - 1);
                    const float* yp = obs + ((size_t)(b0r + m2) * T + tt) * IN + k;
                    ys0 = yp[0]; ys1 = yp[1];
                    ywoff = ((k >> 3) * 16 + m2) * 16 + (k & 7) * 2;
                }
                f16x8 yb, m0, m1, m2f, m3, o0, o1, o2, o3;
                if (hy) yb = *(const f16x8*)(R.ybuf[w & 3] + rd_off);
                if (hm) LOAD_W(R.wbufs[slM][1], m0, m1, m2f, m3);  // i3 out
                if (ho) LOAD_W(R.wbufs[slO][0], o0, o1, o2, o3);   // i6 out
                if (hy) {
                    csty_y = MFMA16(Cy.v, yb, zero4);
                    f32x4 ext;
                    if (w == 0) {
                        f16x8 xb0 = *(const f16x8*)(R.xbuf[0] + rd_off);
                        f32x4 cx = MFMA16(Cx.v, xb0, zero4);
                        hx1 = cx; hx2 = cx;
                        ext = cx;
                    } else {
                        // x_w ~ 3*x_{w-2} - 2*x_{w-3} (cstx is linear in x)
                        ext = 3.f * hx1 - 2.f * hx2;
                    }
                    cst_y = ext + csty_y;
                    uint2 w0p;
                    w0p.x = tanh2_pk(cst_y.x, cst_y.y);
                    w0p.y = tanh2_pk(cst_y.z, cst_y.w);
                    *(uint2*)(R.wbufs[slY][1] + wa) = w0p;         // i1 -> [1]
                }
                if (hm) ITER_BODY(cst_m, m0, m1, m2f, m3, R.wbufs[slM][0]); // i4
                if (ho) ITER_BODY(cst_o, o0, o1, o2, o3, R.wbufs[slO][1]);  // i7
                __syncthreads();
            }
            // ---------- j1: i2(w) || i5(w-1) || EPILOGUE(w-2) (waves 0-1)
            {
                f16x8 c0, c1, c2, c3, m0, m1, m2f, m3;
                if (hy) LOAD_W(R.wbufs[slY][1], c0, c1, c2, c3);   // i1 out
                if (hm) LOAD_W(R.wbufs[slM][0], m0, m1, m2f, m3);  // i4 out
                const bool ep = ho && (wave < 2);
                f16x8 xbp, ybp, w0f, w1f, w2f, w3f;
                if (ep) {
                    xbp = *(const f16x8*)(R.xbuf[w & 1] + rd_off);          // x_{w-2}
                    ybp = *(const f16x8*)(R.ybuf[(w + 2) & 3] + rd_off);    // y_{w-2}
                    LOAD_W(R.wbufs[slO][1], w0f, w1f, w2f, w3f);            // i7 out
                }
                if (hy) ITER_BODY(cst_y, c0, c1, c2, c3, R.wbufs[slY][0]);  // i2
                if (hm) ITER_BODY(cst_m, m0, m1, m2f, m3, R.wbufs[slM][1]); // i5
                if (ep) {
                    f32x4 ea = MFMA16(EPf[0].v, xbp, zero4);
                    f32x4 eb = MFMA16(EPf[1].v, ybp, zero4);
                    ea = MFMA16(EPf[2].v, w0f, ea); eb = MFMA16(EPf[3].v, w1f, eb);
                    ea = MFMA16(EPf[4].v, w2f, ea); eb = MFMA16(EPf[5].v, w3f, eb);
                    f32x4 ez = ea + eb;
                    const int m = l15, tp = w - 2;
                    if (wave == 0 && q < 2) {
                        // rows 0..7: u -> global
                        const size_t o = ((size_t)(b0r + m) * T + tp) * (2 * OUT + 1);
                        out[o + 4 * q + 0] = ez.x; out[o + 4 * q + 1] = ez.y;
                        out[o + 4 * q + 2] = ez.z; out[o + 4 * q + 3] = ez.w;
                    } else if (wave == 0 || q < 2) {
                        // x_next cols: wave0 q2,q3 -> 0..7 ; wave1 q0,q1 -> 8..15
                        const int cb = (wave == 0) ? (4 * q - 8) : (8 + 4 * q);
                        float4 xv = *(const float4*)&R.xs[m][cb];
                        float4 xn;
                        xn.x = fmaf(DT, ez.x, xv.x); xn.y = fmaf(DT, ez.y, xv.y);
                        xn.z = fmaf(DT, ez.z, xv.z); xn.w = fmaf(DT, ez.w, xv.w);
                        *(float4*)&R.xs[m][cb] = xn;
                        // restage x_{w-1} (fp16) into xbuf[(w-1)&1] for i6/ep
                        uint2 pk;
                        pk.x = pkrtz_u(xn.x, xn.y); pk.y = pkrtz_u(xn.z, xn.w);
                        *(uint2*)(R.xbuf[(w + 1) & 1] +
                                  ((cb >> 3) * 16 + m) * 16 + (cb & 7) * 2) = pk;
                    }
                }
                __syncthreads();
            }
            // ---------- j2: i3(w) || i6-exact(w-1); y LDS write
            {
                f16x8 c0, c1, c2, c3, m0, m1, m2f, m3, xbm;
                if (hy) LOAD_W(R.wbufs[slY][0], c0, c1, c2, c3);   // i2 out
                if (hm) {
                    LOAD_W(R.wbufs[slM][1], m0, m1, m2f, m3);      // i5 out
                    xbm = *(const f16x8*)(R.xbuf[(w + 1) & 1] + rd_off); // x_{w-1}
                }
                if (hy) ITER_BODY(cst_y, c0, c1, c2, c3, R.wbufs[slY][1]);  // i3
                if (hm) {
                    f32x4 pc = MFMA16(Cx.v, xbm, csty_m);          // exact cst(w-1)
                    ITER_BODY(pc, m0, m1, m2f, m3, R.wbufs[slM][0]);        // i6
                    hx2 = hx1; hx1 = pc - csty_m;                  // cstx(x_{w-1})
                    cst_m = pc;                                    // i7 uses exact
                }
                if (hy && tid < 256)
                    *(uint*)(R.ybuf[(w + 2) & 3] + ywoff) = pkrtz_u(ys0, ys1);
                __syncthreads();
            }
            // rotate chain state: young -> middle -> old
            cst_o = cst_m; cst_m = cst_y; csty_m = csty_y;
        }
    } else {
        // ================= value branch (fp16 MFMA GEMM) =================
        // out1 = tanh(obs @ W0 + b0); out2 = tanh(out1 @ W1 + b1);
        // value = out2 @ W2 + b2.  Computed transposed: C = W^T(A) * X^T(B).
        // Weights as register A-fragments; inter-layer bounce via wave-private
        // LDS scratch (same-wave DS ordering, no barriers).
        char* scr = sm.v.scr[wave];

        ABu Af0[4], Af1[4][2];
        f32x4 bc0[4], bc1[4];
        float W2v[4][4], lsv[8];
        const float b2v = b2[0];
#pragma unroll
        for (int t2 = 0; t2 < 4; ++t2) {
            const int oc = t2 * 16 + l15;
#pragma unroll
            for (int j = 0; j < 8; ++j) {
                int k = 8 * q + j;
                Af0[t2].h[j]    = (f16)W0[k * 64 + oc];
                Af1[t2][0].h[j] = (f16)W1[k * 64 + oc];
                Af1[t2][1].h[j] = (f16)W1[(32 + k) * 64 + oc];
            }
#pragma unroll
            for (int r = 0; r < 4; ++r) {
                int ocr = t2 * 16 + 4 * q + r;
                bc0[t2][r] = b0[ocr];
                bc1[t2][r] = b1[ocr];
                W2v[t2][r] = W2[ocr];
            }
        }
#pragma unroll
        for (int i = 0; i < 8; ++i) lsv[i] = log_stds[i];

        const size_t rowbase = (size_t)(blockIdx.x - NBLK_R) * 512 + wave * 64;

#pragma unroll
        for (int bt = 0; bt < 4; ++bt) {
            const size_t row = rowbase + bt * 16 + l15;
            // B-frag of obs^T: lane(q,l15) holds feat 8q..8q+7 of batch row l15
            const float* op = obs + row * IN + 8 * q;
            float4 o0 = *(const float4*)op;
            float4 o1 = *(const float4*)(op + 4);
            ABu Bo;
            ((uint*)&Bo.v)[0] = pkrtz_u(o0.x, o0.y);
            ((uint*)&Bo.v)[1] = pkrtz_u(o0.z, o0.w);
            ((uint*)&Bo.v)[2] = pkrtz_u(o1.x, o1.y);
            ((uint*)&Bo.v)[3] = pkrtz_u(o1.z, o1.w);
            // layer0 (K=32) + tanh -> packed h^T into scratch (chunk layout)
#pragma unroll
            for (int t2 = 0; t2 < 4; ++t2) {
                f32x4 a = MFMA16(Af0[t2].v, Bo.v, bc0[t2]);
                uint2 hp;
                hp.x = tanh2_pk(a.x, a.y); hp.y = tanh2_pk(a.z, a.w);
                // k0 = 16*t2 + 4*q: chunk cc = 2*t2 + (q>>1), byte (q&1)*8
                *(uint2*)(scr + ((2 * t2 + (q >> 1)) * 16 + l15) * 16 + (q & 1) * 8) = hp;
            }
            // same-wave DS ops complete in order: no barrier needed
            f16x8 bh0 = *(const f16x8*)(scr + rd_off);
            f16x8 bh1 = *(const f16x8*)(scr + rd_off + 1024);
            // layer1 (K=64) + tanh + W2 dot
            float vpart = 0.f;
#pragma unroll
            for (int t2 = 0; t2 < 4; ++t2) {
                f32x4 a = MFMA16(Af1[t2][0].v, bh0, bc1[t2]);
                a = MFMA16(Af1[t2][1].v, bh1, a);
                vpart = fmaf(fast_tanh(a.x), W2v[t2][0], vpart);
                vpart = fmaf(fast_tanh(a.y), W2v[t2][1], vpart);
                vpart = fmaf(fast_tanh(a.z), W2v[t2][2], vpart);
                vpart = fmaf(fast_tanh(a.w), W2v[t2][3], vpart);
            }
            // reduce over the 4 q-groups (lanes l15, l15+16, l15+32, l15+48)
            vpart += __shfl_xor(vpart, 16);
            vpart += __shfl_xor(vpart, 32);
            const size_t ob = row * (2 * OUT + 1);
            if (q == 0) {
                out[ob + 2 * OUT] = vpart + b2v;
            } else if (q == 1) {
                out[ob + 8]  = lsv[0]; out[ob + 9]  = lsv[1];
                out[ob + 10] = lsv[2]; out[ob + 11] = lsv[3];
            } else if (q == 2) {
                out[ob + 12] = lsv[4]; out[ob + 13] = lsv[5];
                out[ob + 14] = lsv[6]; out[ob + 15] = lsv[7];
            }
        }
    }
}

extern "C" void kernel_launch(void* const* d_in, const int* in_sizes, int n_in,
                              void* d_out, int out_size, void* d_ws, size_t ws_size,
                              hipStream_t stream) {
    const float* obs      = (const float*)d_in[0];
    const float* x0       = (const float*)d_in[1];
    const float* A_T      = (const float*)d_in[2];
    const float* Bw_T     = (const float*)d_in[3];
    const float* By_T     = (const float*)d_in[4];
    const float* Cv_T     = (const float*)d_in[5];
    const float* Dvw_T    = (const float*)d_in[6];
    const float* Dvy_T    = (const float*)d_in[7];
    const float* Cu_T     = (const float*)d_in[8];
    const float* Duw_T    = (const float*)d_in[9];
    const float* Duy_T    = (const float*)d_in[10];
    const float* log_stds = (const float*)d_in[11];
    const float* W0       = (const float*)d_in[12];
    const float* b0       = (const float*)d_in[13];
    const float* W1       = (const float*)d_in[14];
    const float* b1       = (const float*)d_in[15];
    const float* W2       = (const float*)d_in[16];
    const float* b2       = (const float*)d_in[17];
    float* out = (float*)d_out;

    fused_kernel<<<NBLK_R + NBLK_V, NTHR, 0, stream>>>(
        obs, x0, A_T, Bw_T, By_T, Cv_T, Dvw_T, Dvy_T, Cu_T, Duw_T, Duy_T,
        log_stds, W0, b0, W1, b1, W2, b2, out);
}

// Round 6
// 336.729 us; speedup vs baseline: 1.1092x; 1.1092x over previous
//
#include <hip/hip_runtime.h>
#include <cstddef>

#define B 2048
#define T 128
#define S 16
#define NL 128
#define IN 32
#define OUT 8
#define DT 0.01f

// Rinn branch: 7 fixed-point iterations per t, two timesteps software-
// pipelined, 4 rounds/t: r0=[ext-cst+i1 || i5-exact], r1=[i2||i6],
// r2=[i3||i7], r3=[i4||epilogue].  (3-deep pipelining regressed: critical-
// wave imbalance, see round-5 post-mortem.  This is the 257us round-4
// schedule.)
// NEW this round: in-loop barriers are lgkmcnt-only (s_waitcnt lgkmcnt(0) +
// raw s_barrier + sched_barrier(0)) instead of __syncthreads().
// __syncthreads drains vmcnt(0) too, which pulled the y(t+2) HBM load
// latency (~600-900cy) into r0's barrier and the u-store acks into r3's --
// neither is needed: all cross-wave dependencies go through LDS (lgkmcnt),
// y-load results are register-carried to r2 (compiler inserts the vmcnt wait
// at the use, 2 rounds later -> hidden), u-stores have no in-kernel reader.

#define NBLK_R (B / 16)          // 128 rinn blocks, 16 batch rows each
#define NBLK_V ((B * T) / 512)   // 512 value blocks, 512 samples each
#define NTHR 512

typedef unsigned int uint;
typedef _Float16 f16;
typedef f16 f16x8 __attribute__((ext_vector_type(8)));
typedef __fp16 fp16x2_n __attribute__((ext_vector_type(2)));  // native cvt_pkrtz type
typedef float f32x4 __attribute__((ext_vector_type(4)));

union ABu { f16x8 v; f16 h[8]; };

#define MFMA16(A, Bv, C) __builtin_amdgcn_mfma_f32_16x16x32_f16((A), (Bv), (C), 0, 0, 0)

__device__ __forceinline__ uint pkrtz_u(float a, float b) {
    fp16x2_n p = __builtin_amdgcn_cvt_pkrtz(a, b);
    return __builtin_bit_cast(uint, p);
}

// lgkmcnt-only workgroup barrier: drains this wave's DS ops (making its LDS
// writes visible), syncs, and fences post-barrier LDS reads from hoisting.
// Global (vmcnt) traffic intentionally stays in flight across it.
__device__ __forceinline__ void bar_lds() {
    asm volatile("s_waitcnt lgkmcnt(0)" ::: "memory");
    __builtin_amdgcn_s_barrier();
    __builtin_amdgcn_sched_barrier(0);
}

// value branch tanh (has slack, keep safe clamp)
__device__ __forceinline__ float fast_tanh(float x) {
    float e = __expf(fminf(x, 10.f) * 2.f);
    return fmaf(-2.f, __builtin_amdgcn_rcpf(e + 1.f), 1.f);
}

// paired tanh -> packed half2, one shared v_rcp
__device__ __forceinline__ uint tanh2_pk(float a, float b) {
    float ea = __expf(a * 2.f);
    float eb = __expf(b * 2.f);
    float da = ea + 1.f, db = eb + 1.f;
    float r  = __builtin_amdgcn_rcpf(da * db);
    float ta = fmaf(-2.f, db * r, 1.f);
    float tb = fmaf(-2.f, da * r, 1.f);
    return pkrtz_u(ta, tb);
}

// LDS chunk layout for a 16(m) x K(k) fp16 matrix: chunk (cc=k>>3, m) holds 8
// consecutive k of row m at byte ((cc*16+m)*16 + (k&7)*2).  B-fragment read for
// MFMA k-step s (quad q, lane m=l15): one ds_read_b128 at ((s*4+q)*16+m)*16.

struct __align__(16) RinnS {
    char wbufs[2][2][4096];  // per-slot (t&1) w ping-pong buffers (16 x 128 fp16)
    char xbuf[2][1024];      // x_t (f16, K=32 with k>=16 zero pad), per t parity
    char ybuf[4][1024];      // y_t (f16, K=32), ring of 4
    float xs[16][16];        // fp32 master copy of state
};
struct __align__(16) ValueS {
    char scr[8][2048];       // per-wave h^T bounce scratch (64k x 16m fp16)
};
union SmU { RinnS r; ValueS v; };

#define LOAD_W(rb, A0, A1, A2, A3) do { const char* _p = (rb);                 \
    A0 = *(const f16x8*)(_p + rd_off);        A1 = *(const f16x8*)(_p + rd_off + 1024); \
    A2 = *(const f16x8*)(_p + rd_off + 2048); A3 = *(const f16x8*)(_p + rd_off + 3072); } while (0)

#define ITER_BODY(CST, A0, A1, A2, A3, WDST) do {                              \
    f32x4 _p0 = (CST), _p1 = {0.f, 0.f, 0.f, 0.f};                             \
    _p0 = MFMA16(D[0].v, A0, _p0); _p1 = MFMA16(D[1].v, A1, _p1);              \
    _p0 = MFMA16(D[2].v, A2, _p0); _p1 = MFMA16(D[3].v, A3, _p1);              \
    f32x4 _z = _p0 + _p1;                                                      \
    uint2 _w; _w.x = tanh2_pk(_z.x, _z.y); _w.y = tanh2_pk(_z.z, _z.w);        \
    *(uint2*)((WDST) + wa) = _w; } while (0)

__global__ void __launch_bounds__(NTHR, 1)
fused_kernel(const float* __restrict__ obs, const float* __restrict__ x0,
             const float* __restrict__ A_T, const float* __restrict__ Bw_T,
             const float* __restrict__ By_T, const float* __restrict__ Cv_T,
             const float* __restrict__ Dvw_T, const float* __restrict__ Dvy_T,
             const float* __restrict__ Cu_T, const float* __restrict__ Duw_T,
             const float* __restrict__ Duy_T, const float* __restrict__ log_stds,
             const float* __restrict__ W0, const float* __restrict__ b0,
             const float* __restrict__ W1, const float* __restrict__ b1,
             const float* __restrict__ W2, const float* __restrict__ b2,
             float* __restrict__ out) {
    __shared__ SmU sm;
    const int tid = threadIdx.x;
    const int wave = tid >> 6, lane = tid & 63;
    const int q = lane >> 4, l15 = lane & 15;
    const int rd_off = (q * 16 + l15) * 16;  // + s*1024

    if (blockIdx.x < NBLK_R) {
        // ======================= recurrent branch =======================
        RinnS& R = sm.r;
        const int b0r = blockIdx.x * 16;
        const int ct = wave * 16;   // this wave's single 16-col tile of NL

        // ---- iteration-invariant A-operand fragments (fp16) ----
        // Z^T = Dvw^T (A) * w^T (B);  A[c_local][k]: c=ct+l15, k=32s+8q+j
        ABu D[4];
#pragma unroll
        for (int s2 = 0; s2 < 4; ++s2)
#pragma unroll
            for (int j = 0; j < 8; ++j) {
                int k = 32 * s2 + 8 * q + j;
                D[s2].h[j] = (f16)Dvw_T[k * NL + ct + l15];
            }
        // cstx^T = Cv^T (A, K=32 padded) * x^T ; csty^T = Dvy^T (A, K=32) * y^T
        ABu Cx, Cy;
#pragma unroll
        for (int j = 0; j < 8; ++j) {
            int k = 8 * q + j;
            Cx.h[j] = (f16)((k < 16) ? Cv_T[k * NL + ct + l15] : 0.f);
            Cy.h[j] = (f16)Dvy_T[k * NL + ct + l15];
        }
        // epilogue: [u|xn]^T = W^T (A) * [x(32)|y(32)|w(128)]^T (B), K=192
        ABu EPf[6];
        if (wave < 2) {
            int oc = wave * 16 + l15;  // 0..7=u, 8..23=xnext, >=24 pad
#pragma unroll
            for (int s2 = 0; s2 < 6; ++s2)
#pragma unroll
                for (int j = 0; j < 8; ++j) {
                    int k = 32 * s2 + 8 * q + j;
                    float v = 0.f;
                    if (oc < 24) {
                        if (k < 16)       v = (oc < 8) ? Cu_T[k * OUT + oc] : A_T[k * S + (oc - 8)];
                        else if (k >= 32 && k < 64) { int ky = k - 32;
                                          v = (oc < 8) ? Duy_T[ky * OUT + oc] : By_T[ky * S + (oc - 8)]; }
                        else if (k >= 64) { int kw = k - 64;
                                          v = (oc < 8) ? Duw_T[kw * OUT + oc] : Bw_T[kw * S + (oc - 8)]; }
                    }
                    EPf[s2].h[j] = (f16)v;
                }
        }

        // ---- init staging: xs, xbuf[0]=xbuf[1]=x0 (+zero pads), ybuf[0/1]=y0/y1
        if (tid < 256) { int m = tid >> 4, c = tid & 15; R.xs[m][c] = x0[(b0r + m) * S + c]; }
        if (tid < 128) {
            int m = tid >> 3, pr = tid & 7, k = 2 * pr;
            uint u = pkrtz_u(x0[(b0r + m) * S + k], x0[(b0r + m) * S + k + 1]);
            uint off = ((k >> 3) * 16 + m) * 16 + (k & 7) * 2;
            *(uint*)(R.xbuf[0] + off) = u;
            *(uint*)(R.xbuf[1] + off) = u;
        } else if (tid < 384) {   // zero pads: bytes 512..1023 of both xbufs
            int i = tid - 128, buf = i >> 7, d = i & 127;
            *(uint*)(R.xbuf[buf] + 512 + d * 4) = 0u;
        }
        {   // ybuf[0] <- y(0), ybuf[1] <- y(1): 512 pair-slots, one per thread
            int buf = tid >> 8, ii = tid & 255, m = ii >> 4, pr = ii & 15, k = 2 * pr;
            const float* yp = obs + ((size_t)(b0r + m) * T + buf) * IN + k;
            *(uint*)(R.ybuf[buf] + ((k >> 3) * 16 + m) * 16 + (k & 7) * 2) =
                pkrtz_u(yp[0], yp[1]);
        }

        const int wa = (((ct >> 3) + (q >> 1)) * 16 + l15) * 16 + (q & 1) * 8;
        __syncthreads();   // init: full drain once is fine

        f32x4 cst_cur = {0.f, 0.f, 0.f, 0.f}, cst_prv = {0.f, 0.f, 0.f, 0.f};
        f32x4 csty_cur = {0.f, 0.f, 0.f, 0.f}, csty_prv = {0.f, 0.f, 0.f, 0.f};
        f32x4 hx1 = {0.f, 0.f, 0.f, 0.f}, hx2 = {0.f, 0.f, 0.f, 0.f};
        const f32x4 zero4 = {0.f, 0.f, 0.f, 0.f};

        for (int t = 0; t <= T; ++t) {
            const int s = t & 1;
            const bool hc = (t < T);   // current chain (t): i1..i4
            const bool hp = (t > 0);   // previous chain (t-1): i5..i7 + ep
            float ys0 = 0.f, ys1 = 0.f;
            int ywoff = 0;

            // ---------- r0: ext-cst + i1 (t) || i5 exact-cst (t-1); y-loads issue
            {
                if (hc && tid < 256) {   // y(t+2) load issue -> regs (write at r2)
                    int m2 = tid >> 4, pr = tid & 15, k = 2 * pr;
                    int tt = (t + 2 < T) ? (t + 2) : (T - 1);
                    const float* yp = obs + ((size_t)(b0r + m2) * T + tt) * IN + k;
                    ys0 = yp[0]; ys1 = yp[1];
                    ywoff = ((k >> 3) * 16 + m2) * 16 + (k & 7) * 2;
                }
                f16x8 yb, xbp, a0, a1, a2, a3;
                if (hc) yb = *(const f16x8*)(R.ybuf[t & 3] + rd_off);
                if (hp) {
                    xbp = *(const f16x8*)(R.xbuf[s ^ 1] + rd_off);
                    LOAD_W(R.wbufs[s ^ 1][0], a0, a1, a2, a3);   // i4 output
                }
                if (hc) {
                    csty_cur = MFMA16(Cy.v, yb, zero4);
                    f32x4 ext;
                    if (t == 0) {
                        f16x8 xb0 = *(const f16x8*)(R.xbuf[1] + rd_off);
                        f32x4 cx = MFMA16(Cx.v, xb0, zero4);
                        hx1 = cx; hx2 = cx;
                        ext = cx;
                    } else {
                        // 2-step-ahead linear extrapolation from x_{t-2}, x_{t-3}
                        ext = 3.f * hx1 - 2.f * hx2;
                    }
                    cst_cur = ext + csty_cur;
                    uint2 w0p;
                    w0p.x = tanh2_pk(cst_cur.x, cst_cur.y);
                    w0p.y = tanh2_pk(cst_cur.z, cst_cur.w);
                    *(uint2*)(R.wbufs[s][1] + wa) = w0p;         // i1 -> [s][1]
                }
                if (hp) {
                    f32x4 pc = MFMA16(Cx.v, xbp, csty_prv);      // exact cst(t-1)
                    ITER_BODY(pc, a0, a1, a2, a3, R.wbufs[s ^ 1][1]);  // i5
                    hx2 = hx1; hx1 = pc - csty_prv;              // cstx(x_{t-1})
                    cst_prv = pc;                                // i6,i7 use exact
                }
                bar_lds();
            }
            // ---------- r1: i2(t) || i6(t-1)
            {
                f16x8 c0, c1, c2, c3, p0, p1, p2, p3;
                if (hc) LOAD_W(R.wbufs[s][1], c0, c1, c2, c3);       // i1 out
                if (hp) LOAD_W(R.wbufs[s ^ 1][1], p0, p1, p2, p3);   // i5 out
                if (hc) ITER_BODY(cst_cur, c0, c1, c2, c3, R.wbufs[s][0]);
                if (hp) ITER_BODY(cst_prv, p0, p1, p2, p3, R.wbufs[s ^ 1][0]);
                bar_lds();
            }
            // ---------- r2: i3(t) || i7(t-1); y-stage LDS write
            {
                f16x8 c0, c1, c2, c3, p0, p1, p2, p3;
                if (hc) LOAD_W(R.wbufs[s][0], c0, c1, c2, c3);       // i2 out
                if (hp) LOAD_W(R.wbufs[s ^ 1][0], p0, p1, p2, p3);   // i6 out
                if (hc) ITER_BODY(cst_cur, c0, c1, c2, c3, R.wbufs[s][1]);
                if (hp) ITER_BODY(cst_prv, p0, p1, p2, p3, R.wbufs[s ^ 1][1]);
                if (hc && tid < 256)
                    *(uint*)(R.ybuf[(t + 2) & 3] + ywoff) = pkrtz_u(ys0, ys1);
                bar_lds();
            }
            // ---------- r3: i4(t) || EPILOGUE(t-1)  (waves 0-1)
            {
                f16x8 c0, c1, c2, c3;
                if (hc) LOAD_W(R.wbufs[s][1], c0, c1, c2, c3);       // i3 out
                const bool ep = hp && (wave < 2);
                f16x8 xbp, ybp, w0f, w1f, w2f, w3f;
                if (ep) {
                    xbp = *(const f16x8*)(R.xbuf[s ^ 1] + rd_off);
                    ybp = *(const f16x8*)(R.ybuf[(t - 1) & 3] + rd_off);
                    LOAD_W(R.wbufs[s ^ 1][1], w0f, w1f, w2f, w3f);   // i7 out
                }
                if (hc) ITER_BODY(cst_cur, c0, c1, c2, c3, R.wbufs[s][0]);  // i4
                if (ep) {
                    f32x4 ea = MFMA16(EPf[0].v, xbp, zero4);
                    f32x4 eb = MFMA16(EPf[1].v, ybp, zero4);
                    ea = MFMA16(EPf[2].v, w0f, ea); eb = MFMA16(EPf[3].v, w1f, eb);
                    ea = MFMA16(EPf[4].v, w2f, ea); eb = MFMA16(EPf[5].v, w3f, eb);
                    f32x4 ez = ea + eb;
                    const int m = l15, tp = t - 1;
                    if (wave == 0 && q < 2) {
                        // rows 0..7: u -> global (no in-kernel reader, never drained)
                        const size_t o = ((size_t)(b0r + m) * T + tp) * (2 * OUT + 1);
                        out[o + 4 * q + 0] = ez.x; out[o + 4 * q + 1] = ez.y;
                        out[o + 4 * q + 2] = ez.z; out[o + 4 * q + 3] = ez.w;
                    } else if (wave == 0 || q < 2) {
                        // x_next cols: wave0 q2,q3 -> 0..7 ; wave1 q0,q1 -> 8..15
                        const int cb = (wave == 0) ? (4 * q - 8) : (8 + 4 * q);
                        float4 xv = *(const float4*)&R.xs[m][cb];
                        float4 xn;
                        xn.x = fmaf(DT, ez.x, xv.x); xn.y = fmaf(DT, ez.y, xv.y);
                        xn.z = fmaf(DT, ez.z, xv.z); xn.w = fmaf(DT, ez.w, xv.w);
                        *(float4*)&R.xs[m][cb] = xn;
                        // restage x_t (fp16) into xbuf[s] for i5(t) next r0
                        uint2 pk;
                        pk.x = pkrtz_u(xn.x, xn.y); pk.y = pkrtz_u(xn.z, xn.w);
                        *(uint2*)(R.xbuf[s] + ((cb >> 3) * 16 + m) * 16 + (cb & 7) * 2) = pk;
                    }
                }
                bar_lds();
            }
            csty_prv = csty_cur;
        }
    } else {
        // ================= value branch (fp16 MFMA GEMM) =================
        // out1 = tanh(obs @ W0 + b0); out2 = tanh(out1 @ W1 + b1);
        // value = out2 @ W2 + b2.  Computed transposed: C = W^T(A) * X^T(B).
        // Weights as register A-fragments; inter-layer bounce via wave-private
        // LDS scratch (same-wave DS ordering, no barriers).
        char* scr = sm.v.scr[wave];

        ABu Af0[4], Af1[4][2];
        f32x4 bc0[4], bc1[4];
        float W2v[4][4], lsv[8];
        const float b2v = b2[0];
#pragma unroll
        for (int t2 = 0; t2 < 4; ++t2) {
            const int oc = t2 * 16 + l15;
#pragma unroll
            for (int j = 0; j < 8; ++j) {
                int k = 8 * q + j;
                Af0[t2].h[j]    = (f16)W0[k * 64 + oc];
                Af1[t2][0].h[j] = (f16)W1[k * 64 + oc];
                Af1[t2][1].h[j] = (f16)W1[(32 + k) * 64 + oc];
            }
#pragma unroll
            for (int r = 0; r < 4; ++r) {
                int ocr = t2 * 16 + 4 * q + r;
                bc0[t2][r] = b0[ocr];
                bc1[t2][r] = b1[ocr];
                W2v[t2][r] = W2[ocr];
            }
        }
#pragma unroll
        for (int i = 0; i < 8; ++i) lsv[i] = log_stds[i];

        const size_t rowbase = (size_t)(blockIdx.x - NBLK_R) * 512 + wave * 64;

#pragma unroll
        for (int bt = 0; bt < 4; ++bt) {
            const size_t row = rowbase + bt * 16 + l15;
            // B-frag of obs^T: lane(q,l15) holds feat 8q..8q+7 of batch row l15
            const float* op = obs + row * IN + 8 * q;
            float4 o0 = *(const float4*)op;
            float4 o1 = *(const float4*)(op + 4);
            ABu Bo;
            ((uint*)&Bo.v)[0] = pkrtz_u(o0.x, o0.y);
            ((uint*)&Bo.v)[1] = pkrtz_u(o0.z, o0.w);
            ((uint*)&Bo.v)[2] = pkrtz_u(o1.x, o1.y);
            ((uint*)&Bo.v)[3] = pkrtz_u(o1.z, o1.w);
            // layer0 (K=32) + tanh -> packed h^T into scratch (chunk layout)
#pragma unroll
            for (int t2 = 0; t2 < 4; ++t2) {
                f32x4 a = MFMA16(Af0[t2].v, Bo.v, bc0[t2]);
                uint2 hp;
                hp.x = tanh2_pk(a.x, a.y); hp.y = tanh2_pk(a.z, a.w);
                // k0 = 16*t2 + 4*q: chunk cc = 2*t2 + (q>>1), byte (q&1)*8
                *(uint2*)(scr + ((2 * t2 + (q >> 1)) * 16 + l15) * 16 + (q & 1) * 8) = hp;
            }
            // same-wave DS ops complete in order: no barrier needed
            f16x8 bh0 = *(const f16x8*)(scr + rd_off);
            f16x8 bh1 = *(const f16x8*)(scr + rd_off + 1024);
            // layer1 (K=64) + tanh + W2 dot
            float vpart = 0.f;
#pragma unroll
            for (int t2 = 0; t2 < 4; ++t2) {
                f32x4 a = MFMA16(Af1[t2][0].v, bh0, bc1[t2]);
                a = MFMA16(Af1[t2][1].v, bh1, a);
                vpart = fmaf(fast_tanh(a.x), W2v[t2][0], vpart);
                vpart = fmaf(fast_tanh(a.y), W2v[t2][1], vpart);
                vpart = fmaf(fast_tanh(a.z), W2v[t2][2], vpart);
                vpart = fmaf(fast_tanh(a.w), W2v[t2][3], vpart);
            }
            // reduce over the 4 q-groups (lanes l15, l15+16, l15+32, l15+48)
            vpart += __shfl_xor(vpart, 16);
            vpart += __shfl_xor(vpart, 32);
            const size_t ob = row * (2 * OUT + 1);
            if (q == 0) {
                out[ob + 2 * OUT] = vpart + b2v;
            } else if (q == 1) {
                out[ob + 8]  = lsv[0]; out[ob + 9]  = lsv[1];
                out[ob + 10] = lsv[2]; out[ob + 11] = lsv[3];
            } else if (q == 2) {
                out[ob + 12] = lsv[4]; out[ob + 13] = lsv[5];
                out[ob + 14] = lsv[6]; out[ob + 15] = lsv[7];
            }
        }
    }
}

extern "C" void kernel_launch(void* const* d_in, const int* in_sizes, int n_in,
                              void* d_out, int out_size, void* d_ws, size_t ws_size,
                              hipStream_t stream) {
    const float* obs      = (const float*)d_in[0];
    const float* x0       = (const float*)d_in[1];
    const float* A_T      = (const float*)d_in[2];
    const float* Bw_T     = (const float*)d_in[3];
    const float* By_T     = (const float*)d_in[4];
    const float* Cv_T     = (const float*)d_in[5];
    const float* Dvw_T    = (const float*)d_in[6];
    const float* Dvy_T    = (const float*)d_in[7];
    const float* Cu_T     = (const float*)d_in[8];
    const float* Duw_T    = (const float*)d_in[9];
    const float* Duy_T    = (const float*)d_in[10];
    const float* log_stds = (const float*)d_in[11];
    const float* W0       = (const float*)d_in[12];
    const float* b0       = (const float*)d_in[13];
    const float* W1       = (const float*)d_in[14];
    const float* b1       = (const float*)d_in[15];
    const float* W2       = (const float*)d_in[16];
    const float* b2       = (const float*)d_in[17];
    float* out = (float*)d_out;

    fused_kernel<<<NBLK_R + NBLK_V, NTHR, 0, stream>>>(
        obs, x0, A_T, Bw_T, By_T, Cv_T, Dvw_T, Dvy_T, Cu_T, Duw_T, Duy_T,
        log_stds, W0, b0, W1, b1, W2, b2, out);
}